// Round 5
// baseline (198.738 us; speedup 1.0000x reference)
//
#include <hip/hip_runtime.h>

typedef float f32x4 __attribute__((ext_vector_type(4)));
typedef float f32x2 __attribute__((ext_vector_type(2)));

// Compiler memory fence: keeps LDS (and all memory) ops in program order
// across mixed-type reinterpret_cast accesses (TBAA would otherwise allow
// reordering ds_reads before ds_writes -> round-4 Cauchy corruption).
// Zero runtime instructions; per-wave DS pipe is in-order in hardware.
#define LDS_FENCE() asm volatile("" ::: "memory")

// Voigt index pairs (11,22,33,12,13,23)
static constexpr int VII[6] = {0, 1, 2, 0, 0, 1};
static constexpr int VJJ[6] = {0, 1, 2, 1, 2, 2};

// Closed-form Neo-Hookean point evaluation (math verified rounds 1-2,
// fast-math path verified round 4: psi output passed).
template <bool FAST>
__device__ __forceinline__ void nh_compute(const float F[3][3], float c1, float c2,
                                           float& psi, float cau[6], float dd[36])
{
    const float J = F[0][0] * (F[1][1] * F[2][2] - F[1][2] * F[2][1])
                  - F[0][1] * (F[1][0] * F[2][2] - F[1][2] * F[2][0])
                  + F[0][2] * (F[1][0] * F[2][1] - F[1][1] * F[2][0]);

    float b[3][3];
#pragma unroll
    for (int r = 0; r < 3; ++r)
#pragma unroll
        for (int c = 0; c <= r; ++c) {
            const float s = F[r][0] * F[c][0] + F[r][1] * F[c][1] + F[r][2] * F[c][2];
            b[r][c] = s;
            b[c][r] = s;
        }

    const float I1 = b[0][0] + b[1][1] + b[2][2];
    float invJ, Jm23;
    if (FAST) {
        invJ = __builtin_amdgcn_rcpf(J);                                          // v_rcp_f32
        Jm23 = __builtin_amdgcn_exp2f(-(2.0f / 3.0f) * __builtin_amdgcn_logf(J)); // v_exp/v_log (base-2)
    } else {
        invJ = 1.0f / J;
        Jm23 = cbrtf(invJ * invJ);
    }

    psi = c1 * (Jm23 * I1 - 3.0f) + c2 * (J - 1.0f) * (J - 1.0f);

    // Kirchhoff tau = 2 c1 J^{-2/3} (b - (I1/3) I) + 2 c2 (J-1) J I
    const float c1t  = 2.0f * c1 * Jm23;
    const float diag = 2.0f * c2 * (J - 1.0f) * J - c1t * (I1 * (1.0f / 3.0f));
    float tau[3][3];
#pragma unroll
    for (int r = 0; r < 3; ++r)
#pragma unroll
        for (int c = 0; c < 3; ++c)
            tau[r][c] = c1t * b[r][c] + (r == c ? diag : 0.0f);

#pragma unroll
    for (int a = 0; a < 6; ++a)
        cau[a] = tau[VII[a]][VJJ[a]] * invJ;

    const float gE  = 2.0f * c2 * (2.0f * J - 1.0f) * J;
    const float gF  = -2.0f * c2 * (J - 1.0f) * J;
    const float cA  = c1t * (2.0f * I1 * (1.0f / 9.0f));
    const float cB  = c1t * (I1 * (1.0f / 3.0f));
    const float m23 = -(2.0f / 3.0f) * c1t;

    // dd is symmetric: compute upper triangle, mirror.
#pragma unroll
    for (int a = 0; a < 6; ++a) {
        const int i = VII[a], j = VJJ[a];
#pragma unroll
        for (int q = a; q < 6; ++q) {
            const int k = VII[q], l = VJJ[q];
            float s = 0.0f;
            if (i == k) s += c1t * b[j][l];
            if (k == l) s += m23 * b[i][j];
            if (i == j) s += m23 * b[k][l];
            if (i == j && k == l) s += cA + gE;
            if (i == l && j == k) s += cB + gF;
            float g = 0.0f;
            if (j == l) g += tau[i][k];
            if (j == k) g += tau[i][l];
            if (i == l) g += tau[j][k];
            if (i == k) g -= tau[j][l];
            const float v = (s + 0.5f * g) * invJ;
            dd[6 * a + q] = v;
            if (q != a) dd[6 * q + a] = v;
        }
    }
}

// ---------------------------------------------------------------------------
// Main kernel. Per wave: 64 points, all global I/O fully dense via b128,
// LDS round-trips in ds_*_b128 with a LINEAR 16B-unit layout. Wave-private
// buffer -> no s_barrier; LDS_FENCE() pins compile-time order at every
// staging phase boundary. Requires N % 4 == 0.
// ---------------------------------------------------------------------------
#define WPB 4   // waves per block (block = 256)

__global__ __launch_bounds__(256) void nh3d_coal(
    const float* __restrict__ Fg, const float* __restrict__ mp,
    float* __restrict__ out, int N, int nWaves)
{
    __shared__ f32x4 sbuf[WPB][576];   // 9 KiB per wave, 36 KiB per block

    const int tid  = threadIdx.x;
    const int wave = tid >> 6;
    const int lane = tid & 63;
    const int waveIdx = blockIdx.x * WPB + wave;
    if (waveIdx >= nWaves) return;
    const int waveStart = waveIdx * 64;

    const float c1 = mp[0];
    const float c2 = mp[1];

    f32x4* sv = sbuf[wave];
    const float* sf = reinterpret_cast<const float*>(sv);

    // ---- F: dense b128 global load -> LDS -> per-lane record read ---------
    {
        const f32x4* gin = reinterpret_cast<const f32x4*>(Fg + (size_t)waveStart * 9);
        sv[lane]      = gin[lane];
        sv[64 + lane] = gin[64 + lane];
        if (lane < 16) sv[128 + lane] = gin[128 + lane];
    }
    LDS_FENCE();   // stage writes (f32x4) before record reads (float)
    float F[3][3];
#pragma unroll
    for (int r = 0; r < 3; ++r)
#pragma unroll
        for (int c = 0; c < 3; ++c)
            F[r][c] = sf[lane * 9 + 3 * r + c];   // bank 2-way alias: free
    LDS_FENCE();   // record reads before DDSDDE overwrites (WAR)

    float psi, cau[6], dd[36];
    nh_compute<true>(F, c1, c2, psi, cau, dd);

    // ---- psi: dense scalar store ------------------------------------------
    __builtin_nontemporal_store(psi, out + waveStart + lane);

    // ---- DDSDDE: lane record -> LDS (b128), dense b128 read -> NT store ---
#pragma unroll
    for (int q = 0; q < 9; ++q) {
        f32x4 v = {dd[4 * q], dd[4 * q + 1], dd[4 * q + 2], dd[4 * q + 3]};
        sv[lane * 9 + q] = v;
    }
    LDS_FENCE();   // dd writes before dd reads (RAW)

    f32x4* dout = reinterpret_cast<f32x4*>(out + (size_t)7 * N) + (size_t)waveStart * 9;
#pragma unroll
    for (int k = 0; k < 9; ++k)
        __builtin_nontemporal_store(sv[k * 64 + lane], dout + k * 64 + lane);
    LDS_FENCE();   // dd reads before Cauchy overwrites (WAR)

    // ---- Cauchy6: f32x2 stage, 96 f32x4 dense out -------------------------
    {
        f32x2* sv2 = reinterpret_cast<f32x2*>(sv);
#pragma unroll
        for (int t = 0; t < 3; ++t) {
            f32x2 v = {cau[2 * t], cau[2 * t + 1]};
            sv2[lane * 3 + t] = v;
        }
        LDS_FENCE();   // cau writes (f32x2) before cau reads (f32x4) — the r4 bug

        f32x4* cout_ = reinterpret_cast<f32x4*>(out + (size_t)N) + (size_t)waveStart * 6 / 4;
        __builtin_nontemporal_store(sv[lane], cout_ + lane);
        if (lane < 32)
            __builtin_nontemporal_store(sv[64 + lane], cout_ + 64 + lane);
    }
}

// ---------------------------------------------------------------------------
// Fallback / tail: scalar scattered stores (correct for any N).
// ---------------------------------------------------------------------------
__global__ __launch_bounds__(256) void nh3d_scatter(
    const float* __restrict__ Fg, const float* __restrict__ mp,
    float* __restrict__ out, int N, int start)
{
    const int idx = start + blockIdx.x * blockDim.x + threadIdx.x;
    if (idx >= N) return;

    const float c1 = mp[0];
    const float c2 = mp[1];

    float F[3][3];
    {
        const float* fp = Fg + (size_t)idx * 9;
#pragma unroll
        for (int r = 0; r < 3; ++r)
#pragma unroll
            for (int c = 0; c < 3; ++c)
                F[r][c] = fp[3 * r + c];
    }

    float psi, cau[6], dd[36];
    nh_compute<false>(F, c1, c2, psi, cau, dd);

    out[idx] = psi;
    float* cout_ = out + (size_t)N + (size_t)idx * 6;
    float* dout  = out + (size_t)7 * N + (size_t)idx * 36;
#pragma unroll
    for (int a = 0; a < 6; ++a) cout_[a] = cau[a];
#pragma unroll
    for (int a = 0; a < 36; ++a) dout[a] = dd[a];
}

extern "C" void kernel_launch(void* const* d_in, const int* in_sizes, int n_in,
                              void* d_out, int out_size, void* d_ws, size_t ws_size,
                              hipStream_t stream) {
    const int N = in_sizes[0] / 9;
    const float* F_in    = (const float*)d_in[0];
    const float* mat_par = (const float*)d_in[1];
    float* out = (float*)d_out;

    if (N >= 64 && (N % 4) == 0) {
        const int nWaves = N / 64;
        const int grid = (nWaves + WPB - 1) / WPB;
        nh3d_coal<<<grid, 256, 0, stream>>>(F_in, mat_par, out, N, nWaves);
        if (N - nWaves * 64 > 0)
            nh3d_scatter<<<1, 64, 0, stream>>>(F_in, mat_par, out, N, nWaves * 64);
    } else {
        const int grid = (N + 255) / 256;
        nh3d_scatter<<<grid, 256, 0, stream>>>(F_in, mat_par, out, N, 0);
    }
}